// Round 1
// baseline (2300.212 us; speedup 1.0000x reference)
//
#include <hip/hip_runtime.h>
#include <hip/hip_bf16.h>
#include <math.h>

#define HH 32
#define LL 3
#define DS 512
#define DID 128
#define DSTEER 1664
#define DHID 2048
#define HDQ 1024
#define BHROWS 32768

typedef __attribute__((ext_vector_type(8))) short short8;
typedef __attribute__((ext_vector_type(4))) float f32x4;

__device__ __forceinline__ unsigned short f2bf(float f) {
  union { float f; unsigned int u; } x; x.f = f;
  unsigned int r = (x.u + 0x7FFFu + ((x.u >> 16) & 1u)) >> 16;
  return (unsigned short)r;
}
__device__ __forceinline__ unsigned int pk2(float a, float b) {
  return (unsigned int)f2bf(a) | ((unsigned int)f2bf(b) << 16);
}
__device__ __forceinline__ float gelu_exact(float v) {
  return 0.5f * v * (1.0f + erff(v * 0.70710678118654752440f));
}

// ---------- fp32 -> bf16 bulk convert ----------
__global__ void cvt_bf16_kernel(const float4* __restrict__ in, uint2* __restrict__ out, long n4) {
  long i = (long)blockIdx.x * blockDim.x + threadIdx.x;
  long stride = (long)gridDim.x * blockDim.x;
  for (; i < n4; i += stride) {
    float4 v = in[i];
    uint2 o; o.x = pk2(v.x, v.y); o.y = pk2(v.z, v.w);
    out[i] = o;
  }
}

// ---------- RMS-norm + scale -> bf16 (one wave per row of 512) ----------
__global__ void rms_scale_kernel(const float* __restrict__ h,
                                 const float* __restrict__ norm_w,
                                 unsigned short* __restrict__ xn, int layer) {
  int gw = (int)((blockIdx.x * blockDim.x + threadIdx.x) >> 6);
  int lane = threadIdx.x & 63;
  if (gw >= BHROWS) return;
  int head = gw & (HH - 1);
  const float4* hr = (const float4*)(h + (size_t)gw * DS);
  float4 v0 = hr[lane * 2], v1 = hr[lane * 2 + 1];
  float ss = v0.x*v0.x + v0.y*v0.y + v0.z*v0.z + v0.w*v0.w
           + v1.x*v1.x + v1.y*v1.y + v1.z*v1.z + v1.w*v1.w;
  #pragma unroll
  for (int off = 32; off > 0; off >>= 1) ss += __shfl_xor(ss, off, 64);
  float r = rsqrtf(ss * (1.0f / DS) + 1e-6f);
  const float4* nw = (const float4*)(norm_w + ((size_t)head * LL + layer) * DS);
  float4 w0 = nw[lane * 2], w1 = nw[lane * 2 + 1];
  uint4 o;
  o.x = pk2(v0.x * r * w0.x, v0.y * r * w0.y);
  o.y = pk2(v0.z * r * w0.z, v0.w * r * w0.w);
  o.z = pk2(v1.x * r * w1.x, v1.y * r * w1.y);
  o.w = pk2(v1.z * r * w1.z, v1.w * r * w1.w);
  *(uint4*)(xn + (size_t)gw * DS + (size_t)lane * 8) = o;
}

// ---------- 128x128 tile bf16 MFMA GEMM ----------
// A: bf16 [*, lda], logical row r of head maps to global row r*rstep + head.
// B: fp32 [K, ldb] (per-head offset head*b_hstride), converted to bf16 at staging.
// EPI 0: C_f32 = acc + bias
// EPI 1: C_bf16 = gelu(acc + bias)
// EPI 2: C_f32 = acc + bias + resid
template<int EPI>
__global__ __launch_bounds__(256, 2)
void gemm_kernel(const unsigned short* __restrict__ A, int lda, int rstep,
                 const float* __restrict__ Bw, int ldb, long long b_hstride,
                 const float* __restrict__ bias, int bias_hstride,
                 const float* __restrict__ resid, int ldr,
                 void* __restrict__ Cv, int ldc, int K) {
  __shared__ unsigned short lA[128][40];  // 80B rows: frag b128 reads 2-way max
  __shared__ unsigned short lB[128][40];  // transposed: [n][k]
  const int tid = threadIdx.x;
  const int lane = tid & 63;
  const int wave = tid >> 6;
  const int head = blockIdx.z;
  const int tm = blockIdx.y, tn = blockIdx.x;
  const int wm = (wave >> 1) * 64, wn = (wave & 1) * 64;

  // A staging: thread t loads 16 bf16 (32B) of row t>>1, k-half t&1
  const int ar = tid >> 1;
  const int ak = (tid & 1) * 16;
  const unsigned short* Abase = A + ((size_t)(tm * 128 + ar) * rstep + head) * (size_t)lda + ak;
  // B staging: thread t loads 16 fp32 down column (t&127), k-quarter t>>7
  const int bn = tid & 127;
  const int bkk = (tid >> 7) * 16;
  const float* Bbase = Bw + (size_t)head * b_hstride + (size_t)bkk * ldb + (size_t)tn * 128 + bn;

  f32x4 acc[4][4];
  #pragma unroll
  for (int i = 0; i < 4; i++)
    #pragma unroll
    for (int j = 0; j < 4; j++) acc[i][j] = (f32x4){0.f, 0.f, 0.f, 0.f};

  uint4 a0, a1;
  float bv[16];
  // prologue: load K-step 0 into regs
  a0 = *(const uint4*)(Abase);
  a1 = *(const uint4*)(Abase + 8);
  #pragma unroll
  for (int j = 0; j < 16; j++) bv[j] = Bbase[(size_t)j * ldb];

  const int nsteps = K >> 5;
  for (int s = 0; s < nsteps; ++s) {
    __syncthreads();  // previous compute done reading LDS
    *(uint4*)&lA[ar][ak] = a0;
    *(uint4*)&lA[ar][ak + 8] = a1;
    #pragma unroll
    for (int j = 0; j < 8; j++)
      *(unsigned int*)&lB[bn][bkk + 2 * j] = pk2(bv[2 * j], bv[2 * j + 1]);
    __syncthreads();
    if (s + 1 < nsteps) {  // prefetch next K-step (overlaps with MFMA below)
      const unsigned short* ap = Abase + (size_t)(s + 1) * 32;
      a0 = *(const uint4*)(ap);
      a1 = *(const uint4*)(ap + 8);
      const float* bp = Bbase + (size_t)(s + 1) * 32 * ldb;
      #pragma unroll
      for (int j = 0; j < 16; j++) bv[j] = bp[(size_t)j * ldb];
    }
    short8 af[4], bf[4];
    #pragma unroll
    for (int i = 0; i < 4; i++) {
      af[i] = *(const short8*)&lA[wm + i * 16 + (lane & 15)][(lane >> 4) * 8];
      bf[i] = *(const short8*)&lB[wn + i * 16 + (lane & 15)][(lane >> 4) * 8];
    }
    #pragma unroll
    for (int i = 0; i < 4; i++)
      #pragma unroll
      for (int j = 0; j < 4; j++)
        acc[i][j] = __builtin_amdgcn_mfma_f32_16x16x32_bf16(af[i], bf[j], acc[i][j], 0, 0, 0);
  }

  // epilogue
  const float* bptr = bias + (size_t)head * bias_hstride;
  #pragma unroll
  for (int i = 0; i < 4; i++) {
    #pragma unroll
    for (int j = 0; j < 4; j++) {
      #pragma unroll
      for (int r = 0; r < 4; r++) {
        int rowt = wm + i * 16 + (lane >> 4) * 4 + r;
        int colt = wn + j * 16 + (lane & 15);
        int col = tn * 128 + colt;
        size_t crow = (size_t)(tm * 128 + rowt) * rstep + head;
        float v = acc[i][j][r] + bptr[col];
        if (EPI == 1) {
          ((unsigned short*)Cv)[crow * (size_t)ldc + col] = f2bf(gelu_exact(v));
        } else if (EPI == 2) {
          v += resid[crow * (size_t)ldr + col];
          ((float*)Cv)[crow * (size_t)ldc + col] = v;
        } else {
          ((float*)Cv)[crow * (size_t)ldc + col] = v;
        }
      }
    }
  }
}

extern "C" void kernel_launch(void* const* d_in, const int* in_sizes, int n_in,
                              void* d_out, int out_size, void* d_ws, size_t ws_size,
                              hipStream_t stream) {
  const float* x         = (const float*)d_in[0];
  const float* id_in     = (const float*)d_in[1];
  const float* in_proj_w = (const float*)d_in[2];
  const float* in_proj_b = (const float*)d_in[3];
  const float* norm_w    = (const float*)d_in[4];
  const float* up_w      = (const float*)d_in[5];
  const float* up_b      = (const float*)d_in[6];
  const float* down_w    = (const float*)d_in[7];
  const float* down_b    = (const float*)d_in[8];
  const float* q1_w      = (const float*)d_in[9];
  const float* q1_b      = (const float*)d_in[10];
  const float* q2_w      = (const float*)d_in[11];
  const float* q2_b      = (const float*)d_in[12];
  const float* k1_w      = (const float*)d_in[13];
  const float* k1_b      = (const float*)d_in[14];
  const float* k2_w      = (const float*)d_in[15];
  const float* k2_b      = (const float*)d_in[16];
  float* out = (float*)d_out;

  char* ws = (char*)d_ws;
  unsigned short* x_bf  = (unsigned short*)ws; ws += (size_t)BHROWS * DSTEER * 2;  // 109 MB
  unsigned short* id_bf = (unsigned short*)ws; ws += (size_t)BHROWS * DID * 2;     // 8.4 MB
  float*          hbuf  = (float*)ws;          ws += (size_t)BHROWS * DS * 4;      // 67 MB
  unsigned short* xn    = (unsigned short*)ws; ws += (size_t)BHROWS * DS * 2;      // 33.5 MB
  unsigned short* hid   = (unsigned short*)ws; ws += (size_t)BHROWS * DHID * 2;    // 134 MB

  // convert activations to bf16
  cvt_bf16_kernel<<<2048, 256, 0, stream>>>((const float4*)x, (uint2*)x_bf,
                                            (long)BHROWS * DSTEER / 4);
  cvt_bf16_kernel<<<512, 256, 0, stream>>>((const float4*)id_in, (uint2*)id_bf,
                                           (long)BHROWS * DID / 4);

  // q path: q1 (gelu->bf16 hid), q2 -> out[:,512:1536)
  gemm_kernel<1><<<dim3(16, 256, 1), 256, 0, stream>>>(
      x_bf, DSTEER, 1, q1_w, 2 * HDQ, 0, q1_b, 0, nullptr, 0, hid, 2 * HDQ, DSTEER);
  gemm_kernel<0><<<dim3(8, 256, 1), 256, 0, stream>>>(
      hid, 2 * HDQ, 1, q2_w, HDQ, 0, q2_b, 0, nullptr, 0, out + 512, 2560, 2 * HDQ);

  // k path: k1 (gelu->bf16 hid), k2 -> out[:,1536:2560)
  gemm_kernel<1><<<dim3(16, 256, 1), 256, 0, stream>>>(
      id_bf, DID, 1, k1_w, 2 * HDQ, 0, k1_b, 0, nullptr, 0, hid, 2 * HDQ, DID);
  gemm_kernel<0><<<dim3(8, 256, 1), 256, 0, stream>>>(
      hid, 2 * HDQ, 1, k2_w, HDQ, 0, k2_b, 0, nullptr, 0, out + 1536, 2560, 2 * HDQ);

  // content: in_proj (per-head) -> h
  gemm_kernel<0><<<dim3(4, 8, 32), 256, 0, stream>>>(
      x_bf, DSTEER, HH, in_proj_w, DS, (long long)DSTEER * DS, in_proj_b, DS,
      nullptr, 0, hbuf, DS, DSTEER);

  for (int i = 0; i < LL; i++) {
    rms_scale_kernel<<<8192, 256, 0, stream>>>(hbuf, norm_w, xn, i);
    gemm_kernel<1><<<dim3(16, 8, 32), 256, 0, stream>>>(
        xn, DS, HH, up_w + (size_t)i * DS * DHID, DHID, (long long)LL * DS * DHID,
        up_b + (size_t)i * DHID, LL * DHID, nullptr, 0, hid, DHID, DS);
    float* cout = (i < 2) ? hbuf : out;  // last layer writes content into out[:,0:512)
    int ldc = (i < 2) ? DS : 2560;
    gemm_kernel<2><<<dim3(4, 8, 32), 256, 0, stream>>>(
        hid, DHID, HH, down_w + (size_t)i * DHID * DS, DS, (long long)LL * DHID * DS,
        down_b + (size_t)i * DS, LL * DS, hbuf, DS, cout, ldc, DHID);
  }
}

// Round 2
// 2028.572 us; speedup vs baseline: 1.1339x; 1.1339x over previous
//
#include <hip/hip_runtime.h>
#include <hip/hip_bf16.h>
#include <math.h>

#define HH 32
#define LL 3
#define DS 512
#define DID 128
#define DSTEER 1664
#define DHID 2048
#define HDQ 1024
#define BHROWS 32768
#define BK 32

typedef __attribute__((ext_vector_type(8))) short short8;
typedef __attribute__((ext_vector_type(4))) float f32x4;

__device__ __forceinline__ unsigned short f2bf(float f) {
  union { float f; unsigned int u; } x; x.f = f;
  unsigned int r = (x.u + 0x7FFFu + ((x.u >> 16) & 1u)) >> 16;
  return (unsigned short)r;
}
__device__ __forceinline__ unsigned int pk2(float a, float b) {
  return (unsigned int)f2bf(a) | ((unsigned int)f2bf(b) << 16);
}
__device__ __forceinline__ float gelu_exact(float v) {
  return 0.5f * v * (1.0f + erff(v * 0.70710678118654752440f));
}

// ---------- fp32 -> bf16 bulk convert ----------
__global__ void cvt_bf16_kernel(const float4* __restrict__ in, uint2* __restrict__ out, long n4) {
  long i = (long)blockIdx.x * blockDim.x + threadIdx.x;
  long stride = (long)gridDim.x * blockDim.x;
  for (; i < n4; i += stride) {
    float4 v = in[i];
    uint2 o; o.x = pk2(v.x, v.y); o.y = pk2(v.z, v.w);
    out[i] = o;
  }
}

// ---------- batched transpose + convert: fp32 [R][C] -> bf16 [C][R] ----------
// tile: 32 rows x 64 cols. grid = (C/64, R/32, batch)
__global__ void transpose_cvt_kernel(const float* __restrict__ in, long long in_bstride,
                                     unsigned short* __restrict__ out, long long out_bstride,
                                     int R, int C) {
  __shared__ float t[64][33];
  const int r0 = blockIdx.y * 32;
  const int c0 = blockIdx.x * 64;
  const float* bin = in + (long long)blockIdx.z * in_bstride;
  unsigned short* bout = out + (long long)blockIdx.z * out_bstride;
  const int tid = threadIdx.x;
  const int col = tid & 63, rr = tid >> 6;
  #pragma unroll
  for (int j = 0; j < 8; j++) {
    int r = j * 4 + rr;
    t[col][r] = bin[(size_t)(r0 + r) * C + c0 + col];
  }
  __syncthreads();
  const int rq = (tid & 7) * 4;
  const int cc = tid >> 3;
  #pragma unroll
  for (int j = 0; j < 2; j++) {
    int c = j * 32 + cc;
    float v0 = t[c][rq], v1 = t[c][rq + 1], v2 = t[c][rq + 2], v3 = t[c][rq + 3];
    uint2 o; o.x = pk2(v0, v1); o.y = pk2(v2, v3);
    *(uint2*)&bout[(size_t)(c0 + c) * R + r0 + rq] = o;
  }
}

// ---------- RMS-norm + scale -> bf16 (one wave per row of 512) ----------
__global__ void rms_scale_kernel(const float* __restrict__ h,
                                 const float* __restrict__ norm_w,
                                 unsigned short* __restrict__ xn, int layer) {
  int gw = (int)((blockIdx.x * blockDim.x + threadIdx.x) >> 6);
  int lane = threadIdx.x & 63;
  if (gw >= BHROWS) return;
  int head = gw & (HH - 1);
  const float4* hr = (const float4*)(h + (size_t)gw * DS);
  float4 v0 = hr[lane * 2], v1 = hr[lane * 2 + 1];
  float ss = v0.x*v0.x + v0.y*v0.y + v0.z*v0.z + v0.w*v0.w
           + v1.x*v1.x + v1.y*v1.y + v1.z*v1.z + v1.w*v1.w;
  #pragma unroll
  for (int off = 32; off > 0; off >>= 1) ss += __shfl_xor(ss, off, 64);
  float r = rsqrtf(ss * (1.0f / DS) + 1e-6f);
  const float4* nw = (const float4*)(norm_w + ((size_t)head * LL + layer) * DS);
  float4 w0 = nw[lane * 2], w1 = nw[lane * 2 + 1];
  uint4 o;
  o.x = pk2(v0.x * r * w0.x, v0.y * r * w0.y);
  o.y = pk2(v0.z * r * w0.z, v0.w * r * w0.w);
  o.z = pk2(v1.x * r * w1.x, v1.y * r * w1.y);
  o.w = pk2(v1.z * r * w1.z, v1.w * r * w1.w);
  *(uint4*)(xn + (size_t)gw * DS + (size_t)lane * 8) = o;
}

// ---------- 128x128 tile bf16 MFMA GEMM, global_load_lds staging ----------
// A: bf16 [*, lda], logical row r of head -> global row r*rstep + head.
// Bt: bf16 [N][K] per-head (transposed weights), ldb = K.
// EPI 0: C_f32 = acc + bias ; EPI 1: C_bf16 = gelu(acc+bias) ; EPI 2: C_f32 = acc+bias+resid
template<int EPI>
__global__ __launch_bounds__(256, 2)
void gemm_kernel(const unsigned short* __restrict__ A, int lda, int rstep,
                 const unsigned short* __restrict__ Bt, int ldb, long long b_hstride,
                 const float* __restrict__ bias, int bias_hstride,
                 const float* __restrict__ resid, int ldr,
                 void* __restrict__ Cv, int ldc, int K) {
  __shared__ unsigned short lds[2 * 128 * BK];
  unsigned short* lA = lds;
  unsigned short* lB = lds + 128 * BK;
  const int tid = threadIdx.x;
  const int lane = tid & 63;
  const int wave = tid >> 6;
  const int head = blockIdx.z;
  const int tm = blockIdx.y, tn = blockIdx.x;
  const int wm = (wave >> 1) * 64, wn = (wave & 1) * 64;

  // staging: wave w owns rows [w*32, w*32+32): two 16-row segments, one
  // global_load_lds(16B) each. lane l -> row = seg*16 + (l>>2), slot = l&3.
  // XOR-swizzle: LDS slot c holds global k-quarter c ^ ((row>>1)&3)
  // (inverse-swizzled SOURCE + swizzled READ; LDS itself stays linear).
  const int srow0 = wave * 32 + (lane >> 2);
  const int srow1 = srow0 + 16;
  const int sslot = lane & 3;
  const int sq0 = (sslot ^ ((srow0 >> 1) & 3)) * 8;
  const int sq1 = (sslot ^ ((srow1 >> 1) & 3)) * 8;

  const unsigned short* Asrc0 = A + ((size_t)(tm * 128 + srow0) * rstep + head) * lda + sq0;
  const unsigned short* Asrc1 = A + ((size_t)(tm * 128 + srow1) * rstep + head) * lda + sq1;
  const unsigned short* Bh = Bt + (size_t)head * b_hstride;
  const unsigned short* Bsrc0 = Bh + (size_t)(tn * 128 + srow0) * ldb + sq0;
  const unsigned short* Bsrc1 = Bh + (size_t)(tn * 128 + srow1) * ldb + sq1;
  unsigned short* ldsA0 = lA + (size_t)(wave * 32) * BK;
  unsigned short* ldsA1 = lA + (size_t)(wave * 32 + 16) * BK;
  unsigned short* ldsB0 = lB + (size_t)(wave * 32) * BK;
  unsigned short* ldsB1 = lB + (size_t)(wave * 32 + 16) * BK;

#define STAGE(k0) do { \
    __builtin_amdgcn_global_load_lds((const __attribute__((address_space(1))) unsigned int*)(Asrc0 + (k0)), \
                                     (__attribute__((address_space(3))) unsigned int*)ldsA0, 16, 0, 0); \
    __builtin_amdgcn_global_load_lds((const __attribute__((address_space(1))) unsigned int*)(Asrc1 + (k0)), \
                                     (__attribute__((address_space(3))) unsigned int*)ldsA1, 16, 0, 0); \
    __builtin_amdgcn_global_load_lds((const __attribute__((address_space(1))) unsigned int*)(Bsrc0 + (k0)), \
                                     (__attribute__((address_space(3))) unsigned int*)ldsB0, 16, 0, 0); \
    __builtin_amdgcn_global_load_lds((const __attribute__((address_space(1))) unsigned int*)(Bsrc1 + (k0)), \
                                     (__attribute__((address_space(3))) unsigned int*)ldsB1, 16, 0, 0); \
  } while (0)

  f32x4 acc[4][4];
  #pragma unroll
  for (int i = 0; i < 4; i++)
    #pragma unroll
    for (int j = 0; j < 4; j++) acc[i][j] = (f32x4){0.f, 0.f, 0.f, 0.f};

  const int nsteps = K >> 5;
  STAGE(0);
  for (int s = 0; s < nsteps; ++s) {
    __syncthreads();  // staged data visible (compiler drains vmcnt before barrier)
    short8 af[4], bfr[4];
    #pragma unroll
    for (int i = 0; i < 4; i++) {
      int ra = wm + i * 16 + (lane & 15);
      af[i] = *(const short8*)&lA[(size_t)ra * BK + (((lane >> 4) ^ ((ra >> 1) & 3)) * 8)];
      int rb = wn + i * 16 + (lane & 15);
      bfr[i] = *(const short8*)&lB[(size_t)rb * BK + (((lane >> 4) ^ ((rb >> 1) & 3)) * 8)];
    }
    __syncthreads();  // all waves done reading LDS
    if (s + 1 < nsteps) STAGE((s + 1) * BK);  // overlap next stage with MFMA
    #pragma unroll
    for (int i = 0; i < 4; i++)
      #pragma unroll
      for (int j = 0; j < 4; j++)
        acc[i][j] = __builtin_amdgcn_mfma_f32_16x16x32_bf16(af[i], bfr[j], acc[i][j], 0, 0, 0);
  }
#undef STAGE

  // epilogue
  const float* bptr = bias + (size_t)head * bias_hstride;
  #pragma unroll
  for (int i = 0; i < 4; i++) {
    #pragma unroll
    for (int j = 0; j < 4; j++) {
      #pragma unroll
      for (int r = 0; r < 4; r++) {
        int rowt = wm + i * 16 + (lane >> 4) * 4 + r;
        int colt = wn + j * 16 + (lane & 15);
        int col = tn * 128 + colt;
        size_t crow = (size_t)(tm * 128 + rowt) * rstep + head;
        float v = acc[i][j][r] + bptr[col];
        if (EPI == 1) {
          ((unsigned short*)Cv)[crow * (size_t)ldc + col] = f2bf(gelu_exact(v));
        } else if (EPI == 2) {
          v += resid[crow * (size_t)ldr + col];
          ((float*)Cv)[crow * (size_t)ldc + col] = v;
        } else {
          ((float*)Cv)[crow * (size_t)ldc + col] = v;
        }
      }
    }
  }
}

extern "C" void kernel_launch(void* const* d_in, const int* in_sizes, int n_in,
                              void* d_out, int out_size, void* d_ws, size_t ws_size,
                              hipStream_t stream) {
  const float* x         = (const float*)d_in[0];
  const float* id_in     = (const float*)d_in[1];
  const float* in_proj_w = (const float*)d_in[2];
  const float* in_proj_b = (const float*)d_in[3];
  const float* norm_w    = (const float*)d_in[4];
  const float* up_w      = (const float*)d_in[5];
  const float* up_b      = (const float*)d_in[6];
  const float* down_w    = (const float*)d_in[7];
  const float* down_b    = (const float*)d_in[8];
  const float* q1_w      = (const float*)d_in[9];
  const float* q1_b      = (const float*)d_in[10];
  const float* q2_w      = (const float*)d_in[11];
  const float* q2_b      = (const float*)d_in[12];
  const float* k1_w      = (const float*)d_in[13];
  const float* k1_b      = (const float*)d_in[14];
  const float* k2_w      = (const float*)d_in[15];
  const float* k2_b      = (const float*)d_in[16];
  float* out = (float*)d_out;

  char* ws = (char*)d_ws;
  unsigned short* x_bf  = (unsigned short*)ws; ws += (size_t)BHROWS * DSTEER * 2;  // 109 MB
  unsigned short* id_bf = (unsigned short*)ws; ws += (size_t)BHROWS * DID * 2;     // 8.4 MB
  float*          hbuf  = (float*)ws;          ws += (size_t)BHROWS * DS * 4;      // 67 MB
  unsigned short* xn    = (unsigned short*)ws; ws += (size_t)BHROWS * DS * 2;      // 33.5 MB
  unsigned short* hid   = (unsigned short*)ws; ws += (size_t)BHROWS * DHID * 2;    // 134 MB
  unsigned short* wbuf  = (unsigned short*)ws; ws += (size_t)HH * DHID * DS * 2;   // 67 MB (reused)

  // activations -> bf16
  cvt_bf16_kernel<<<2048, 256, 0, stream>>>((const float4*)x, (uint2*)x_bf,
                                            (long)BHROWS * DSTEER / 4);
  cvt_bf16_kernel<<<512, 256, 0, stream>>>((const float4*)id_in, (uint2*)id_bf,
                                           (long)BHROWS * DID / 4);

  // ---- q path ----
  transpose_cvt_kernel<<<dim3(2 * HDQ / 64, DSTEER / 32, 1), 256, 0, stream>>>(
      q1_w, 0, wbuf, 0, DSTEER, 2 * HDQ);
  gemm_kernel<1><<<dim3(16, 256, 1), 256, 0, stream>>>(
      x_bf, DSTEER, 1, wbuf, DSTEER, 0, q1_b, 0, nullptr, 0, hid, 2 * HDQ, DSTEER);
  transpose_cvt_kernel<<<dim3(HDQ / 64, 2 * HDQ / 32, 1), 256, 0, stream>>>(
      q2_w, 0, wbuf, 0, 2 * HDQ, HDQ);
  gemm_kernel<0><<<dim3(8, 256, 1), 256, 0, stream>>>(
      hid, 2 * HDQ, 1, wbuf, 2 * HDQ, 0, q2_b, 0, nullptr, 0, out + 512, 2560, 2 * HDQ);

  // ---- k path ----
  transpose_cvt_kernel<<<dim3(2 * HDQ / 64, DID / 32, 1), 256, 0, stream>>>(
      k1_w, 0, wbuf, 0, DID, 2 * HDQ);
  gemm_kernel<1><<<dim3(16, 256, 1), 256, 0, stream>>>(
      id_bf, DID, 1, wbuf, DID, 0, k1_b, 0, nullptr, 0, hid, 2 * HDQ, DID);
  transpose_cvt_kernel<<<dim3(HDQ / 64, 2 * HDQ / 32, 1), 256, 0, stream>>>(
      k2_w, 0, wbuf, 0, 2 * HDQ, HDQ);
  gemm_kernel<0><<<dim3(8, 256, 1), 256, 0, stream>>>(
      hid, 2 * HDQ, 1, wbuf, 2 * HDQ, 0, k2_b, 0, nullptr, 0, out + 1536, 2560, 2 * HDQ);

  // ---- content: in_proj (per-head) ----
  transpose_cvt_kernel<<<dim3(DS / 64, DSTEER / 32, HH), 256, 0, stream>>>(
      in_proj_w, (long long)DSTEER * DS, wbuf, (long long)DS * DSTEER, DSTEER, DS);
  gemm_kernel<0><<<dim3(4, 8, 32), 256, 0, stream>>>(
      x_bf, DSTEER, HH, wbuf, DSTEER, (long long)DS * DSTEER, in_proj_b, DS,
      nullptr, 0, hbuf, DS, DSTEER);

  for (int i = 0; i < LL; i++) {
    rms_scale_kernel<<<8192, 256, 0, stream>>>(hbuf, norm_w, xn, i);
    transpose_cvt_kernel<<<dim3(DHID / 64, DS / 32, HH), 256, 0, stream>>>(
        up_w + (size_t)i * DS * DHID, (long long)LL * DS * DHID,
        wbuf, (long long)DHID * DS, DS, DHID);
    gemm_kernel<1><<<dim3(16, 8, 32), 256, 0, stream>>>(
        xn, DS, HH, wbuf, DS, (long long)DHID * DS,
        up_b + (size_t)i * DHID, LL * DHID, nullptr, 0, hid, DHID, DS);
    transpose_cvt_kernel<<<dim3(DS / 64, DHID / 32, HH), 256, 0, stream>>>(
        down_w + (size_t)i * DHID * DS, (long long)LL * DHID * DS,
        wbuf, (long long)DS * DHID, DHID, DS);
    float* cout = (i < 2) ? hbuf : out;  // last layer -> out[:,0:512)
    int ldc = (i < 2) ? DS : 2560;
    gemm_kernel<2><<<dim3(4, 8, 32), 256, 0, stream>>>(
        hid, DHID, HH, wbuf, DHID, (long long)DS * DHID,
        down_b + (size_t)i * DS, LL * DS, hbuf, DS, cout, ldc, DHID);
  }
}

// Round 3
// 1706.646 us; speedup vs baseline: 1.3478x; 1.1886x over previous
//
#include <hip/hip_runtime.h>
#include <hip/hip_bf16.h>
#include <math.h>

#define HH 32
#define LL 3
#define DS 512
#define DID 128
#define DSTEER 1664
#define DHID 2048
#define HDQ 1024
#define BHROWS 32768

typedef __attribute__((ext_vector_type(8))) short short8;
typedef __attribute__((ext_vector_type(4))) float f32x4;

typedef const __attribute__((address_space(1))) unsigned int* gptr_t;
typedef __attribute__((address_space(3))) unsigned int* lptr_t;

#define FENCE() asm volatile("" ::: "memory")
#define BAR() do { FENCE(); __builtin_amdgcn_s_barrier(); FENCE(); } while (0)
#define VMCNT4() asm volatile("s_waitcnt vmcnt(4)" ::: "memory")
#define VMCNT2() asm volatile("s_waitcnt vmcnt(2)" ::: "memory")
#define VMCNT0() asm volatile("s_waitcnt vmcnt(0)" ::: "memory")

__device__ __forceinline__ unsigned short f2bf(float f) {
  union { float f; unsigned int u; } x; x.f = f;
  unsigned int r = (x.u + 0x7FFFu + ((x.u >> 16) & 1u)) >> 16;
  return (unsigned short)r;
}
__device__ __forceinline__ unsigned int pk2(float a, float b) {
  return (unsigned int)f2bf(a) | ((unsigned int)f2bf(b) << 16);
}
__device__ __forceinline__ float gelu_exact(float v) {
  return 0.5f * v * (1.0f + erff(v * 0.70710678118654752440f));
}

// ---------- fp32 -> bf16 bulk convert ----------
__global__ void cvt_bf16_kernel(const float4* __restrict__ in, uint2* __restrict__ out, long n4) {
  long i = (long)blockIdx.x * blockDim.x + threadIdx.x;
  long stride = (long)gridDim.x * blockDim.x;
  for (; i < n4; i += stride) {
    float4 v = in[i];
    uint2 o; o.x = pk2(v.x, v.y); o.y = pk2(v.z, v.w);
    out[i] = o;
  }
}

// ---------- batched transpose + convert: fp32 [R][C] -> bf16 [C][R] ----------
__global__ void transpose_cvt_kernel(const float* __restrict__ in, long long in_bstride,
                                     unsigned short* __restrict__ out, long long out_bstride,
                                     int R, int C) {
  __shared__ float t[64][33];
  const int r0 = blockIdx.y * 32;
  const int c0 = blockIdx.x * 64;
  const float* bin = in + (long long)blockIdx.z * in_bstride;
  unsigned short* bout = out + (long long)blockIdx.z * out_bstride;
  const int tid = threadIdx.x;
  const int col = tid & 63, rr = tid >> 6;
  #pragma unroll
  for (int j = 0; j < 8; j++) {
    int r = j * 4 + rr;
    t[col][r] = bin[(size_t)(r0 + r) * C + c0 + col];
  }
  __syncthreads();
  const int rq = (tid & 7) * 4;
  const int cc = tid >> 3;
  #pragma unroll
  for (int j = 0; j < 2; j++) {
    int c = j * 32 + cc;
    float v0 = t[c][rq], v1 = t[c][rq + 1], v2 = t[c][rq + 2], v3 = t[c][rq + 3];
    uint2 o; o.x = pk2(v0, v1); o.y = pk2(v2, v3);
    *(uint2*)&bout[(size_t)(c0 + c) * R + r0 + rq] = o;
  }
}

// ---------- RMS-norm + scale -> bf16 ----------
__global__ void rms_scale_kernel(const float* __restrict__ h,
                                 const float* __restrict__ norm_w,
                                 unsigned short* __restrict__ xn, int layer) {
  int gw = (int)((blockIdx.x * blockDim.x + threadIdx.x) >> 6);
  int lane = threadIdx.x & 63;
  if (gw >= BHROWS) return;
  int head = gw & (HH - 1);
  const float4* hr = (const float4*)(h + (size_t)gw * DS);
  float4 v0 = hr[lane * 2], v1 = hr[lane * 2 + 1];
  float ss = v0.x*v0.x + v0.y*v0.y + v0.z*v0.z + v0.w*v0.w
           + v1.x*v1.x + v1.y*v1.y + v1.z*v1.z + v1.w*v1.w;
  #pragma unroll
  for (int off = 32; off > 0; off >>= 1) ss += __shfl_xor(ss, off, 64);
  float r = rsqrtf(ss * (1.0f / DS) + 1e-6f);
  const float4* nw = (const float4*)(norm_w + ((size_t)head * LL + layer) * DS);
  float4 w0 = nw[lane * 2], w1 = nw[lane * 2 + 1];
  uint4 o;
  o.x = pk2(v0.x * r * w0.x, v0.y * r * w0.y);
  o.y = pk2(v0.z * r * w0.z, v0.w * r * w0.w);
  o.z = pk2(v1.x * r * w1.x, v1.y * r * w1.y);
  o.w = pk2(v1.z * r * w1.z, v1.w * r * w1.w);
  *(uint4*)(xn + (size_t)gw * DS + (size_t)lane * 8) = o;
}

// ---------- 256x256 tile, BK=64, 8-wave, 8-phase-style pipelined bf16 GEMM ----------
// A: bf16, logical row r of head -> global row r*rstep + head. Bt: bf16 [N][K] per head.
// LDS: 2 buffers x (A[256][64] + B[256][64]) = 128 KiB.
// A halves: h0 = 64-row blocks {0,2}, h1 = {1,3} (natural LDS rows).
// B halves: even/odd 32-row granules; LDS row = (g&1)*128 + (g>>1)*32 + (n&31).
// K-slot swizzle: LDS 16B-slot s at row r holds global k-slot s ^ (r&7)
// (inverse-swizzled global source + swizzled ds_read; LDS writes stay linear).
template<int EPI>
__global__ __launch_bounds__(512, 2)
void gemm256_kernel(const unsigned short* __restrict__ A, int lda, int rstep,
                    const unsigned short* __restrict__ Bt, int ldb, long long b_hstride,
                    const float* __restrict__ bias, int bias_hstride,
                    const float* __restrict__ resid, int ldr,
                    void* __restrict__ Cv, int ldc, int K) {
  __shared__ unsigned short lds[2 * 2 * 256 * 64];  // 128 KiB
  const int tid = threadIdx.x;
  const int lane = tid & 63;
  const int wave = tid >> 6;
  const int wr = wave >> 2, wc = wave & 3;
  const int head = blockIdx.z;
  const int gx = gridDim.x;
  const int nwg = gx * gridDim.y;
  int wgid = blockIdx.y * gx + blockIdx.x;
  { int cpx = nwg >> 3; wgid = (wgid & 7) * cpx + (wgid >> 3); }  // bijective: nwg%8==0
  const int tn = wgid % gx, tm = wgid / gx;

  // ---- staging addressing (per-lane source, linear LDS dest) ----
  const int l3 = lane >> 3;                   // 0..7
  const int gslot = ((lane & 7) ^ l3) * 8;    // inverse-swizzled k offset (elements)
  const int mbase = wave * 8 + l3;
  const int nbase = (wave >> 2) * 64 + (wave & 3) * 8 + l3;
  const unsigned short* pA = A + ((size_t)(tm * 256 + mbase) * rstep + head) * lda + gslot;
  const unsigned short* pB = Bt + (size_t)head * b_hstride
                               + (size_t)(tn * 256 + nbase) * ldb + gslot;
  const size_t aBlk = (size_t)64 * rstep * lda;

  // ---- fragment read addressing ----
  const int physk0 = ((lane >> 4) ^ (lane & 7)) * 8;
  const int physk1 = ((4 + (lane >> 4)) ^ (lane & 7)) * 8;
  const int aRow = wr * 128 + (lane & 15);
  const int bRow = wc * 32 + (lane & 15);

  auto stageA = [&](unsigned short* dstA, int h, size_t kels) {
    #pragma unroll
    for (int i = 0; i < 2; ++i)
      __builtin_amdgcn_global_load_lds(
          (gptr_t)(pA + (size_t)(i * 2 + h) * aBlk + kels),
          (lptr_t)(dstA + ((i * 2 + h) * 64 + wave * 8) * 64), 16, 0, 0);
  };
  auto stageB = [&](unsigned short* dstB, int h, size_t kels) {
    #pragma unroll
    for (int i = 0; i < 2; ++i)
      __builtin_amdgcn_global_load_lds(
          (gptr_t)(pB + (size_t)(i * 128 + h * 32) * ldb + kels),
          (lptr_t)(dstB + (h * 128 + i * 64 + wave * 8) * 64), 16, 0, 0);
  };

  f32x4 acc[8][4];
  #pragma unroll
  for (int i = 0; i < 8; ++i)
    #pragma unroll
    for (int j = 0; j < 4; ++j) acc[i][j] = (f32x4){0.f, 0.f, 0.f, 0.f};
  short8 a[4][2], b[4][2];

  // ---- prologue: stage K-tile 0 (order: A-h0, B-h0, B-h1, A-h1) ----
  stageA(lds, 0, 0);
  stageB(lds + 16384, 0, 0);
  stageB(lds + 16384, 1, 0);
  stageA(lds, 1, 0);
  VMCNT4();  // A-h0 + B-h0 complete
  BAR();

  const int T = K >> 6;
  for (int t = 0; t < T; ++t) {
    unsigned short* rA = lds + (t & 1) * 32768;
    unsigned short* rB = rA + 16384;
    unsigned short* wA = lds + ((t + 1) & 1) * 32768;
    unsigned short* wB = wA + 16384;
    const size_t kn = (size_t)(t + 1) * 64;
    const bool more = (t + 1 < T);

    // ======== phase A: read A frags 0-3 + B frags 0-1; stage A-h0(t+1) ========
    #pragma unroll
    for (int i = 0; i < 4; ++i) {
      a[i][0] = *(const short8*)&rA[(aRow + i * 16) * 64 + physk0];
      a[i][1] = *(const short8*)&rA[(aRow + i * 16) * 64 + physk1];
    }
    #pragma unroll
    for (int j = 0; j < 2; ++j) {
      b[j][0] = *(const short8*)&rB[(bRow + j * 16) * 64 + physk0];
      b[j][1] = *(const short8*)&rB[(bRow + j * 16) * 64 + physk1];
    }
    if (more) stageA(wA, 0, kn);
    BAR();
    __builtin_amdgcn_s_setprio(1);
    #pragma unroll
    for (int i = 0; i < 4; ++i)
      #pragma unroll
      for (int j = 0; j < 2; ++j) {
        acc[i][j] = __builtin_amdgcn_mfma_f32_16x16x32_bf16(a[i][0], b[j][0], acc[i][j], 0, 0, 0);
        acc[i][j] = __builtin_amdgcn_mfma_f32_16x16x32_bf16(a[i][1], b[j][1], acc[i][j], 0, 0, 0);
      }
    __builtin_amdgcn_s_setprio(0);
    if (more) VMCNT4(); else VMCNT2();  // B-h1(t) ready for phase B
    BAR();

    // ======== phase B: read B frags 2-3; stage B-h0(t+1) ========
    #pragma unroll
    for (int j = 0; j < 2; ++j) {
      b[2 + j][0] = *(const short8*)&rB[(128 + bRow + j * 16) * 64 + physk0];
      b[2 + j][1] = *(const short8*)&rB[(128 + bRow + j * 16) * 64 + physk1];
    }
    if (more) stageB(wB, 0, kn);
    BAR();
    __builtin_amdgcn_s_setprio(1);
    #pragma unroll
    for (int i = 0; i < 4; ++i)
      #pragma unroll
      for (int j = 0; j < 2; ++j) {
        acc[i][2 + j] = __builtin_amdgcn_mfma_f32_16x16x32_bf16(a[i][0], b[2 + j][0], acc[i][2 + j], 0, 0, 0);
        acc[i][2 + j] = __builtin_amdgcn_mfma_f32_16x16x32_bf16(a[i][1], b[2 + j][1], acc[i][2 + j], 0, 0, 0);
      }
    __builtin_amdgcn_s_setprio(0);
    if (more) VMCNT4(); else VMCNT0();  // A-h1(t) ready for phase C
    BAR();

    // ======== phase C: read A frags 4-7; stage B-h1(t+1) ========
    #pragma unroll
    for (int i = 0; i < 4; ++i) {
      a[i][0] = *(const short8*)&rA[(aRow + (4 + i) * 16) * 64 + physk0];
      a[i][1] = *(const short8*)&rA[(aRow + (4 + i) * 16) * 64 + physk1];
    }
    if (more) stageB(wB, 1, kn);
    BAR();
    __builtin_amdgcn_s_setprio(1);
    #pragma unroll
    for (int i = 0; i < 4; ++i)
      #pragma unroll
      for (int j = 0; j < 2; ++j) {
        acc[4 + i][2 + j] = __builtin_amdgcn_mfma_f32_16x16x32_bf16(a[i][0], b[2 + j][0], acc[4 + i][2 + j], 0, 0, 0);
        acc[4 + i][2 + j] = __builtin_amdgcn_mfma_f32_16x16x32_bf16(a[i][1], b[2 + j][1], acc[4 + i][2 + j], 0, 0, 0);
      }
    __builtin_amdgcn_s_setprio(0);
    BAR();

    // ======== phase D: stage A-h1(t+1) ========
    if (more) stageA(wA, 1, kn);
    BAR();
    __builtin_amdgcn_s_setprio(1);
    #pragma unroll
    for (int i = 0; i < 4; ++i)
      #pragma unroll
      for (int j = 0; j < 2; ++j) {
        acc[4 + i][j] = __builtin_amdgcn_mfma_f32_16x16x32_bf16(a[i][0], b[j][0], acc[4 + i][j], 0, 0, 0);
        acc[4 + i][j] = __builtin_amdgcn_mfma_f32_16x16x32_bf16(a[i][1], b[j][1], acc[4 + i][j], 0, 0, 0);
      }
    __builtin_amdgcn_s_setprio(0);
    if (more) VMCNT4();  // A-h0 + B-h0 (t+1) ready for next phase A
    BAR();
  }

  // ---- epilogue ----
  const float* bptr = bias + (size_t)head * bias_hstride;
  #pragma unroll
  for (int i = 0; i < 8; ++i) {
    #pragma unroll
    for (int j = 0; j < 4; ++j) {
      #pragma unroll
      for (int r = 0; r < 4; ++r) {
        int rowt = wr * 128 + i * 16 + (lane >> 4) * 4 + r;
        int colt = wc * 64 + j * 16 + (lane & 15);
        int col = tn * 256 + colt;
        size_t crow = (size_t)(tm * 256 + rowt) * rstep + head;
        float v = acc[i][j][r] + bptr[col];
        if (EPI == 1) {
          ((unsigned short*)Cv)[crow * (size_t)ldc + col] = f2bf(gelu_exact(v));
        } else if (EPI == 2) {
          v += resid[crow * (size_t)ldr + col];
          ((float*)Cv)[crow * (size_t)ldc + col] = v;
        } else {
          ((float*)Cv)[crow * (size_t)ldc + col] = v;
        }
      }
    }
  }
}

extern "C" void kernel_launch(void* const* d_in, const int* in_sizes, int n_in,
                              void* d_out, int out_size, void* d_ws, size_t ws_size,
                              hipStream_t stream) {
  const float* x         = (const float*)d_in[0];
  const float* id_in     = (const float*)d_in[1];
  const float* in_proj_w = (const float*)d_in[2];
  const float* in_proj_b = (const float*)d_in[3];
  const float* norm_w    = (const float*)d_in[4];
  const float* up_w      = (const float*)d_in[5];
  const float* up_b      = (const float*)d_in[6];
  const float* down_w    = (const float*)d_in[7];
  const float* down_b    = (const float*)d_in[8];
  const float* q1_w      = (const float*)d_in[9];
  const float* q1_b      = (const float*)d_in[10];
  const float* q2_w      = (const float*)d_in[11];
  const float* q2_b      = (const float*)d_in[12];
  const float* k1_w      = (const float*)d_in[13];
  const float* k1_b      = (const float*)d_in[14];
  const float* k2_w      = (const float*)d_in[15];
  const float* k2_b      = (const float*)d_in[16];
  float* out = (float*)d_out;

  char* ws = (char*)d_ws;
  unsigned short* x_bf  = (unsigned short*)ws; ws += (size_t)BHROWS * DSTEER * 2;  // 109 MB
  unsigned short* id_bf = (unsigned short*)ws; ws += (size_t)BHROWS * DID * 2;     // 8.4 MB
  float*          hbuf  = (float*)ws;          ws += (size_t)BHROWS * DS * 4;      // 67 MB
  unsigned short* xn    = (unsigned short*)ws; ws += (size_t)BHROWS * DS * 2;      // 33.5 MB
  unsigned short* hid   = (unsigned short*)ws; ws += (size_t)BHROWS * DHID * 2;    // 134 MB
  unsigned short* wbuf  = (unsigned short*)ws; ws += (size_t)HH * DHID * DS * 2;   // 67 MB (reused)

  // activations -> bf16
  cvt_bf16_kernel<<<2048, 256, 0, stream>>>((const float4*)x, (uint2*)x_bf,
                                            (long)BHROWS * DSTEER / 4);
  cvt_bf16_kernel<<<512, 256, 0, stream>>>((const float4*)id_in, (uint2*)id_bf,
                                           (long)BHROWS * DID / 4);

  // ---- q path ----
  transpose_cvt_kernel<<<dim3(2 * HDQ / 64, DSTEER / 32, 1), 256, 0, stream>>>(
      q1_w, 0, wbuf, 0, DSTEER, 2 * HDQ);
  gemm256_kernel<1><<<dim3(8, 128, 1), 512, 0, stream>>>(
      x_bf, DSTEER, 1, wbuf, DSTEER, 0, q1_b, 0, nullptr, 0, hid, 2 * HDQ, DSTEER);
  transpose_cvt_kernel<<<dim3(HDQ / 64, 2 * HDQ / 32, 1), 256, 0, stream>>>(
      q2_w, 0, wbuf, 0, 2 * HDQ, HDQ);
  gemm256_kernel<0><<<dim3(4, 128, 1), 512, 0, stream>>>(
      hid, 2 * HDQ, 1, wbuf, 2 * HDQ, 0, q2_b, 0, nullptr, 0, out + 512, 2560, 2 * HDQ);

  // ---- k path ----
  transpose_cvt_kernel<<<dim3(2 * HDQ / 64, DID / 32, 1), 256, 0, stream>>>(
      k1_w, 0, wbuf, 0, DID, 2 * HDQ);
  gemm256_kernel<1><<<dim3(8, 128, 1), 512, 0, stream>>>(
      id_bf, DID, 1, wbuf, DID, 0, k1_b, 0, nullptr, 0, hid, 2 * HDQ, DID);
  transpose_cvt_kernel<<<dim3(HDQ / 64, 2 * HDQ / 32, 1), 256, 0, stream>>>(
      k2_w, 0, wbuf, 0, 2 * HDQ, HDQ);
  gemm256_kernel<0><<<dim3(4, 128, 1), 512, 0, stream>>>(
      hid, 2 * HDQ, 1, wbuf, 2 * HDQ, 0, k2_b, 0, nullptr, 0, out + 1536, 2560, 2 * HDQ);

  // ---- content: in_proj (per-head) ----
  transpose_cvt_kernel<<<dim3(DS / 64, DSTEER / 32, HH), 256, 0, stream>>>(
      in_proj_w, (long long)DSTEER * DS, wbuf, (long long)DS * DSTEER, DSTEER, DS);
  gemm256_kernel<0><<<dim3(2, 4, 32), 512, 0, stream>>>(
      x_bf, DSTEER, HH, wbuf, DSTEER, (long long)DS * DSTEER, in_proj_b, DS,
      nullptr, 0, hbuf, DS, DSTEER);

  for (int i = 0; i < LL; i++) {
    rms_scale_kernel<<<8192, 256, 0, stream>>>(hbuf, norm_w, xn, i);
    transpose_cvt_kernel<<<dim3(DHID / 64, DS / 32, HH), 256, 0, stream>>>(
        up_w + (size_t)i * DS * DHID, (long long)LL * DS * DHID,
        wbuf, (long long)DHID * DS, DS, DHID);
    gemm256_kernel<1><<<dim3(8, 4, 32), 512, 0, stream>>>(
        xn, DS, HH, wbuf, DS, (long long)DHID * DS,
        up_b + (size_t)i * DHID, LL * DHID, nullptr, 0, hid, DHID, DS);
    transpose_cvt_kernel<<<dim3(DS / 64, DHID / 32, HH), 256, 0, stream>>>(
        down_w + (size_t)i * DHID * DS, (long long)LL * DHID * DS,
        wbuf, (long long)DS * DHID, DHID, DS);
    float* cout = (i < 2) ? hbuf : out;  // last layer -> out[:,0:512)
    int ldc = (i < 2) ? DS : 2560;
    gemm256_kernel<2><<<dim3(2, 4, 32), 512, 0, stream>>>(
        hid, DHID, HH, wbuf, DHID, (long long)DS * DHID,
        down_b + (size_t)i * DS, LL * DS, hbuf, DS, cout, ldc, DHID);
  }
}